// Round 7
// baseline (877.442 us; speedup 1.0000x reference)
//
#include <hip/hip_runtime.h>
#include <hip/hip_bf16.h>

#define LEAKY 0.2f

// ---------------- CSR build ----------------

__global__ void k_zero_int(int* __restrict__ p, int n) {
    int i = blockIdx.x * blockDim.x + threadIdx.x;
    if (i < n) p[i] = 0;
}

__global__ void k_hist(const int* __restrict__ dst, int* __restrict__ cnt, int E, int N) {
    int e = blockIdx.x * blockDim.x + threadIdx.x;
    if (e >= E) return;
    int dn = dst[e];
    if ((unsigned)dn < (unsigned)N) atomicAdd(&cnt[dn], 1);
}

// single-block exclusive scan, shuffle-based (wave scan + cross-wave combine)
__global__ __launch_bounds__(1024)
void k_scan(const int* __restrict__ cnt, int* __restrict__ row_start,
            int* __restrict__ cursor, int N) {
    __shared__ int wsum[16];
    __shared__ int carry_s;
    const int tid  = threadIdx.x;
    const int wave = tid >> 6;
    const int lane = tid & 63;
    if (tid == 0) carry_s = 0;
    __syncthreads();
    for (int base = 0; base < N; base += 1024) {
        int i = base + tid;
        int v = (i < N) ? cnt[i] : 0;
        int x = v;
        #pragma unroll
        for (int off = 1; off < 64; off <<= 1) {
            int t = __shfl_up(x, off, 64);
            if (lane >= off) x += t;
        }
        if (lane == 63) wsum[wave] = x;
        __syncthreads();
        if (wave == 0 && lane < 16) {
            int y = wsum[lane];
            #pragma unroll
            for (int off = 1; off < 16; off <<= 1) {
                int t = __shfl_up(y, off, 64);
                if (lane >= off) y += t;
            }
            wsum[lane] = y;
        }
        __syncthreads();
        int carry = carry_s;
        int wbase = (wave > 0) ? wsum[wave - 1] : 0;
        int excl  = carry + wbase + x - v;
        if (i < N) { row_start[i] = excl; cursor[i] = excl; }
        int tot = wsum[15];
        __syncthreads();
        if (tid == 0) carry_s = carry + tot;
        __syncthreads();
    }
    if (tid == 0) row_start[N] = carry_s;
}

__global__ void k_scatter(const int* __restrict__ src, const int* __restrict__ dst,
                          int* __restrict__ cursor, int* __restrict__ src_sorted,
                          int E, int N) {
    int e = blockIdx.x * blockDim.x + threadIdx.x;
    if (e >= E) return;
    int dn = dst[e];
    if ((unsigned)dn >= (unsigned)N) return;
    int pos = atomicAdd(&cursor[dn], 1);
    src_sorted[pos] = src[e];
}

// ---------------- GEMM kernels (f32) ----------------
// 128x64 tile, 8x4 micro-tile (used for M=64)

__global__ __launch_bounds__(256)
void k_gemm64(const float* __restrict__ A, const float* __restrict__ B,
              float* __restrict__ C, int N, int K, int M) {
    __shared__ float As[16][132];
    __shared__ float Bs[16][68];
    const int tid = threadIdx.x;
    const int tx = tid & 15;
    const int ty = tid >> 4;
    const int row0 = blockIdx.y * 128;
    const int col0 = blockIdx.x * 64;

    const int arow = tid >> 2;
    const int acol = (tid & 3) * 4;
    const int brow = tid >> 4;
    const int bcol = (tid & 15) * 4;

    float acc[8][4] = {};

    for (int k0 = 0; k0 < K; k0 += 16) {
        #pragma unroll
        for (int p = 0; p < 2; ++p) {
            int r = arow + p * 64;
            int gr = row0 + r;
            float4 av = make_float4(0.f, 0.f, 0.f, 0.f);
            if (gr < N) av = *(const float4*)(A + (size_t)gr * K + k0 + acol);
            As[acol + 0][r] = av.x;
            As[acol + 1][r] = av.y;
            As[acol + 2][r] = av.z;
            As[acol + 3][r] = av.w;
        }
        {
            float4 bv = *(const float4*)(B + (size_t)(k0 + brow) * M + col0 + bcol);
            Bs[brow][bcol + 0] = bv.x;
            Bs[brow][bcol + 1] = bv.y;
            Bs[brow][bcol + 2] = bv.z;
            Bs[brow][bcol + 3] = bv.w;
        }
        __syncthreads();

        #pragma unroll
        for (int kk = 0; kk < 16; ++kk) {
            float a[8], b[4];
            #pragma unroll
            for (int i = 0; i < 8; ++i) a[i] = As[kk][ty * 8 + i];
            #pragma unroll
            for (int j = 0; j < 4; ++j) b[j] = Bs[kk][tx * 4 + j];
            #pragma unroll
            for (int i = 0; i < 8; ++i)
                #pragma unroll
                for (int j = 0; j < 4; ++j)
                    acc[i][j] = fmaf(a[i], b[j], acc[i][j]);
        }
        __syncthreads();
    }

    #pragma unroll
    for (int i = 0; i < 8; ++i) {
        int r = row0 + ty * 8 + i;
        if (r < N) {
            float4 o = make_float4(acc[i][0], acc[i][1], acc[i][2], acc[i][3]);
            *(float4*)(C + (size_t)r * M + col0 + tx * 4) = o;
        }
    }
}

// 128x128 tile, 8x8 micro-tile (used for M multiple of 128)
__global__ __launch_bounds__(256)
void k_gemm128(const float* __restrict__ A, const float* __restrict__ B,
               float* __restrict__ C, int N, int K, int M) {
    __shared__ float As[16][132];
    __shared__ float Bs[16][132];
    const int tid = threadIdx.x;
    const int tx = tid & 15;
    const int ty = tid >> 4;
    const int row0 = blockIdx.y * 128;
    const int col0 = blockIdx.x * 128;

    const int arow = tid >> 2;
    const int acol = (tid & 3) * 4;
    const int brow = tid >> 5;
    const int bcol = (tid & 31) * 4;

    float acc[8][8] = {};

    for (int k0 = 0; k0 < K; k0 += 16) {
        #pragma unroll
        for (int p = 0; p < 2; ++p) {
            int r = arow + p * 64;
            int gr = row0 + r;
            float4 av = make_float4(0.f, 0.f, 0.f, 0.f);
            if (gr < N) av = *(const float4*)(A + (size_t)gr * K + k0 + acol);
            As[acol + 0][r] = av.x;
            As[acol + 1][r] = av.y;
            As[acol + 2][r] = av.z;
            As[acol + 3][r] = av.w;
        }
        #pragma unroll
        for (int p = 0; p < 2; ++p) {
            int r = brow + p * 8;
            float4 bv = *(const float4*)(B + (size_t)(k0 + r) * M + col0 + bcol);
            Bs[r][bcol + 0] = bv.x;
            Bs[r][bcol + 1] = bv.y;
            Bs[r][bcol + 2] = bv.z;
            Bs[r][bcol + 3] = bv.w;
        }
        __syncthreads();

        #pragma unroll
        for (int kk = 0; kk < 16; ++kk) {
            float a[8], b[8];
            #pragma unroll
            for (int i = 0; i < 8; ++i) a[i] = As[kk][ty * 8 + i];
            #pragma unroll
            for (int j = 0; j < 8; ++j) b[j] = Bs[kk][tx * 8 + j];
            #pragma unroll
            for (int i = 0; i < 8; ++i)
                #pragma unroll
                for (int j = 0; j < 8; ++j)
                    acc[i][j] = fmaf(a[i], b[j], acc[i][j]);
        }
        __syncthreads();
    }

    #pragma unroll
    for (int i = 0; i < 8; ++i) {
        int r = row0 + ty * 8 + i;
        if (r < N) {
            *(float4*)(C + (size_t)r * M + col0 + tx * 8) =
                make_float4(acc[i][0], acc[i][1], acc[i][2], acc[i][3]);
            *(float4*)(C + (size_t)r * M + col0 + tx * 8 + 4) =
                make_float4(acc[i][4], acc[i][5], acc[i][6], acc[i][7]);
        }
    }
}

// ---------------- attention pieces (CSR, atomic-free) ----------------

// one wave per (node,head): lane = d, coalesced feat read, shuffle reduce
__global__ __launch_bounds__(256)
void k_el_er(const float* __restrict__ feat, const float* __restrict__ al,
             const float* __restrict__ ar, float* __restrict__ el,
             float* __restrict__ er, int NH, int H) {
    int g = blockIdx.x * 4 + (threadIdx.x >> 6);
    int lane = threadIdx.x & 63;
    if (g >= NH) return;
    int h = g % H;
    float v  = feat[(size_t)g * 64 + lane];
    float sl = v * al[h * 64 + lane];
    float sr = v * ar[h * 64 + lane];
    #pragma unroll
    for (int off = 32; off; off >>= 1) {
        sl += __shfl_down(sl, off, 64);
        sr += __shfl_down(sr, off, 64);
    }
    if (lane == 0) { el[g] = sl; er[g] = sr; }
}

// per (node, head): online softmax max+sum over incoming edges, then a
// second pass writes the normalized weight per sorted edge: w[i*H+h].
// (one exp per (edge,head) total — NOT per lane; threads are h-fastest so
// the w writes of the H threads of one node are 4-contiguous.)
__global__ void k_node_msw(const int* __restrict__ row_start, const int* __restrict__ src_sorted,
                           const float* __restrict__ el, const float* __restrict__ er,
                           float* __restrict__ w, int N, int H) {
    int idx = blockIdx.x * blockDim.x + threadIdx.x;
    if (idx >= N * H) return;
    int n = idx / H;
    int h = idx - n * H;
    float erv = er[idx];
    int b0 = row_start[n], b1 = row_start[n + 1];
    float mx = -INFINITY, sum = 0.f;
    for (int i = b0; i < b1; ++i) {
        float x = el[src_sorted[i] * H + h] + erv;
        x = (x > 0.f) ? x : LEAKY * x;
        if (x > mx) { sum = sum * __expf(mx - x) + 1.f; mx = x; }
        else        { sum += __expf(x - mx); }
    }
    float rs = 1.0f / fmaxf(sum, 1e-30f);
    for (int i = b0; i < b1; ++i) {
        float x = el[src_sorted[i] * H + h] + erv;
        x = (x > 0.f) ? x : LEAKY * x;
        w[(size_t)i * H + h] = __expf(x - mx) * rs;
    }
}

// Aggregation: 256 threads = (256/M) node-groups; each group of M threads
// owns one dst node, thread owns one (h,d) slot. 4-wide pipelined gather;
// weights are precomputed per (edge,head) — wave-uniform loads.
__global__ __launch_bounds__(256)
void k_agg_csr(const int* __restrict__ row_start, const int* __restrict__ src_sorted,
               const float* __restrict__ feat, const float* __restrict__ w,
               const float* __restrict__ bias, float* __restrict__ out,
               int H, int N, int do_relu) {
    const int M = H * 64;
    const int G = 256 / M;
    const int grp = threadIdx.x / M;
    const int tid = threadIdx.x - grp * M;
    const int n = blockIdx.x * G + grp;
    if (n >= N) return;
    const int h = tid >> 6;

    float acc = bias[tid];
    int b0 = row_start[n], b1 = row_start[n + 1];
    int i = b0;
    for (; i + 4 <= b1; i += 4) {
        int s0 = src_sorted[i], s1 = src_sorted[i + 1];
        int s2 = src_sorted[i + 2], s3 = src_sorted[i + 3];
        float w0 = w[(size_t)i * H + h];
        float w1 = w[(size_t)(i + 1) * H + h];
        float w2 = w[(size_t)(i + 2) * H + h];
        float w3 = w[(size_t)(i + 3) * H + h];
        float f0 = feat[(size_t)s0 * M + tid];
        float f1 = feat[(size_t)s1 * M + tid];
        float f2 = feat[(size_t)s2 * M + tid];
        float f3 = feat[(size_t)s3 * M + tid];
        acc = fmaf(f0, w0, acc);
        acc = fmaf(f1, w1, acc);
        acc = fmaf(f2, w2, acc);
        acc = fmaf(f3, w3, acc);
    }
    for (; i < b1; ++i) {
        int sn = src_sorted[i];
        float wv = w[(size_t)i * H + h];
        acc = fmaf(feat[(size_t)sn * M + tid], wv, acc);
    }
    if (do_relu) acc = fmaxf(acc, 0.f);
    out[(size_t)n * M + tid] = acc;
}

// ---------------- host side ----------------

static void run_layer(const float* A, int K, const float* W,
                      const float* al_, const float* ar_, const float* b_, int H,
                      float* feat, float* rstOut,
                      float* el, float* er, float* w,
                      const int* row_start, const int* src_sorted,
                      int N, int E, bool do_relu, hipStream_t stream) {
    const int M = H * 64;
    if (M % 128 == 0) {
        dim3 gg(M / 128, (N + 127) / 128);
        k_gemm128<<<gg, 256, 0, stream>>>(A, W, feat, N, K, M);
    } else {
        dim3 gg(M / 64, (N + 127) / 128);
        k_gemm64<<<gg, 256, 0, stream>>>(A, W, feat, N, K, M);
    }

    int nh = N * H;
    k_el_er<<<(nh + 3) / 4, 256, 0, stream>>>(feat, al_, ar_, el, er, nh, H);
    k_node_msw<<<(nh + 255) / 256, 256, 0, stream>>>(row_start, src_sorted, el, er, w, N, H);

    int G = 256 / M;
    k_agg_csr<<<(N + G - 1) / G, 256, 0, stream>>>(row_start, src_sorted, feat, w,
                                                   b_, rstOut, H, N, do_relu ? 1 : 0);
}

extern "C" void kernel_launch(void* const* d_in, const int* in_sizes, int n_in,
                              void* d_out, int out_size, void* d_ws, size_t ws_size,
                              hipStream_t stream) {
    const float* features = (const float*)d_in[0];
    const int*   src = (const int*)d_in[1];
    const int*   dst = (const int*)d_in[2];
    const float* W1  = (const float*)d_in[3];
    const float* al1 = (const float*)d_in[4];
    const float* ar1 = (const float*)d_in[5];
    const float* b1  = (const float*)d_in[6];
    const float* W2  = (const float*)d_in[7];
    const float* al2 = (const float*)d_in[8];
    const float* ar2 = (const float*)d_in[9];
    const float* b2  = (const float*)d_in[10];
    const float* W3  = (const float*)d_in[11];
    const float* al3 = (const float*)d_in[12];
    const float* ar3 = (const float*)d_in[13];
    const float* b3  = (const float*)d_in[14];

    const int N = in_sizes[0] / 128;   // 50000
    const int E = in_sizes[1];         // 800000

    float* ws   = (float*)d_ws;
    size_t n256 = (size_t)N * 256;
    float* bufA = ws;                        // [N,256]
    float* bufB = bufA + n256;               // [N,256]
    float* el   = bufB + n256;               // [N,4]
    float* er   = el + (size_t)N * 4;        // [N,4]
    float* w    = er + (size_t)N * 4;        // [E,4]
    int* cnt        = (int*)(w + (size_t)E * 4);   // [N]
    int* row_start  = cnt + N;                      // [N+1]
    int* cursor     = row_start + N + 1;            // [N]
    int* src_sorted = cursor + N;                   // [E]

    // ---- build dst-CSR (every call; deterministic, graph-capture safe) ----
    k_zero_int<<<(N + 255) / 256, 256, 0, stream>>>(cnt, N);
    k_hist<<<(E + 255) / 256, 256, 0, stream>>>(dst, cnt, E, N);
    k_scan<<<1, 1024, 0, stream>>>(cnt, row_start, cursor, N);
    k_scatter<<<(E + 255) / 256, 256, 0, stream>>>(src, dst, cursor, src_sorted, E, N);

    // layer 1: A=features[N,128] -> feat=bufB[N,256] -> rst=bufA[N,256] (+relu)
    run_layer(features, 128, W1, al1, ar1, b1, 4, bufB, bufA,
              el, er, w, row_start, src_sorted, N, E, true, stream);
    // layer 2
    run_layer(bufA, 256, W2, al2, ar2, b2, 4, bufB, bufA,
              el, er, w, row_start, src_sorted, N, E, true, stream);
    // layer 3: H=1; mean over 1 head is identity -> write straight to d_out
    run_layer(bufA, 256, W3, al3, ar3, b3, 1, bufB, (float*)d_out,
              el, er, w, row_start, src_sorted, N, E, false, stream);
}